// Round 3
// baseline (353.661 us; speedup 1.0000x reference)
//
#include <hip/hip_runtime.h>
#include <cstddef>
#include <cstdint>

typedef __bf16 bf16x8 __attribute__((ext_vector_type(8)));
typedef float  f32x4  __attribute__((ext_vector_type(4)));

#define X_STRIDE 936   // 928 cols + 8 pad (bf16) -> 468 dwords/row: 2-way max LDS bank aliasing
#define H1_STRIDE 66
#define WTC_ELEMS (128 * 928)
#define WTC_BYTES (WTC_ELEMS * 2)

__device__ __forceinline__ float b2f(unsigned short u) {
    unsigned int x = (unsigned int)u << 16;
    return __builtin_bit_cast(float, x);
}
__device__ __forceinline__ unsigned short f2b(float f) {
    unsigned int u = __builtin_bit_cast(unsigned int, f);
    u += 0x7FFFu + ((u >> 16) & 1u);   // RNE
    return (unsigned short)(u >> 16);
}

// Build WTc[128][928] bf16 from fp32 weights (row-major, row = output col n, col = X col k).
//  n 0..63   : W1[k][n] for k<864, else 0
//  n 64..95  : head_W: X cols 544..799 -> rows 0..255, X cols 864..927 -> rows 256..319
//  n 96..127 : tail_W, same mapping
__global__ void prep_weights(const float* __restrict__ W1,
                             const float* __restrict__ headW,
                             const float* __restrict__ tailW,
                             unsigned short* __restrict__ WTc) {
    const int n = blockIdx.x;
    for (int k = threadIdx.x; k < 928; k += blockDim.x) {
        float v = 0.f;
        if (n < 64) {
            if (k < 864) v = W1[(size_t)k * 64 + n];
        } else {
            const int c = (n < 96) ? (n - 64) : (n - 96);
            const float* W = (n < 96) ? headW : tailW;
            if (k >= 544 && k < 800)      v = W[(size_t)(k - 544) * 32 + c];
            else if (k >= 864 && k < 928) v = W[(size_t)(256 + (k - 864)) * 32 + c];
        }
        WTc[(size_t)n * 928 + k] = f2b(v);
    }
}

// Fallback B-fragment gather straight from fp32 W1/headW/tailW natural layouts.
__device__ __forceinline__ bf16x8 gather_Bfrag(const float* __restrict__ W1,
                                               const float* __restrict__ hW,
                                               const float* __restrict__ tW,
                                               int n, int k0) {
    unsigned short r[8];
    if (n < 64) {
        #pragma unroll
        for (int j = 0; j < 8; ++j) {
            const int k = k0 + j;
            r[j] = (k < 864) ? f2b(W1[(size_t)k * 64 + n]) : (unsigned short)0;
        }
    } else {
        const float* W = (n < 96) ? hW : tW;
        const int c = (n < 96) ? (n - 64) : (n - 96);
        #pragma unroll
        for (int j = 0; j < 8; ++j) {
            const int k = k0 + j;
            float v = 0.f;
            if (k >= 544 && k < 800)      v = W[(size_t)(k - 544) * 32 + c];
            else if (k >= 864 && k < 928) v = W[(size_t)(256 + (k - 864)) * 32 + c];
            r[j] = f2b(v);
        }
    }
    unsigned short tmp[8];
    #pragma unroll
    for (int j = 0; j < 8; ++j) tmp[j] = r[j];
    return __builtin_bit_cast(bf16x8, *(const uint4*)tmp);
}

// X-row layout (bf16): [0,256) head_repr | [256,512) tail_repr | [512,544) rel_repr |
// [544,800) mid_repr | [800,832) head_feat | [832,864) tail_feat | [864,928) dist_repr
template <bool USE_WTC>
__global__ __launch_bounds__(256, 2) void fused_main(
    const float* __restrict__ node_repr,   // [N*256] fp32
    const float* __restrict__ node_feat,   // [N*32]  fp32
    const int* __restrict__ head_idx,
    const int* __restrict__ rel_idx,
    const int* __restrict__ tail_idx,
    const int* __restrict__ dist,
    const int* __restrict__ inter,         // [B*32]
    const float* __restrict__ rel_emb,     // [200*32]
    const float* __restrict__ dist_emb,    // [11*64]
    const float* __restrict__ b1p,         // [64]
    const float* __restrict__ head_bp,     // [32]
    const float* __restrict__ tail_bp,     // [32]
    const float* __restrict__ W2p,         // [64*32]
    const float* __restrict__ b2p,         // [32]
    const float* __restrict__ W3p,         // [32]
    const float* __restrict__ b3p,         // [1]
    const unsigned short* __restrict__ WTc,// [128*928] bf16 (only if USE_WTC)
    const float* __restrict__ W1p,         // natural fp32 layouts (fallback)
    const float* __restrict__ headWp,
    const float* __restrict__ tailWp,
    float* __restrict__ out,
    int B)
{
    extern __shared__ char smem[];
    unsigned short* sX  = (unsigned short*)smem;                       // 32 * 936 bf16 = 59904 B
    unsigned short* sH1 = (unsigned short*)(smem + 32 * X_STRIDE * 2); // 32 * 66 bf16  =  4224 B

    const int tid  = threadIdx.x;
    const int w    = tid >> 6;
    const int lane = tid & 63;
    const int g0   = blockIdx.x * 32;

    // ---------- Phase 0: zero ALL dynamic LDS (cheap insurance) ----------
    {
        uint32_t* z = (uint32_t*)smem;
        const int nwords = (32 * X_STRIDE + 32 * H1_STRIDE) / 2;   // 16032
        for (int i = tid; i < nwords; i += 256) z[i] = 0u;
    }
    __syncthreads();

    float* out0   = out;
    float* out_hp = out + B;
    float* out_tp = out + B + (size_t)B * 32;
    float* out_hf = out + B + (size_t)B * 64;
    float* out_tf = out + B + (size_t)B * 96;

    // ---------- Phase 1: gather + build X tile (fp32 -> bf16) ----------
    for (int li = 0; li < 8; ++li) {
        const int L = w * 8 + li;
        const int g = g0 + L;
        if (g >= B) continue;

        const int hidx = head_idx[g];
        const int tidx = tail_idx[g];
        const int ridx = rel_idx[g];
        const int didx = dist[g];
        const int c4 = lane * 4;

        // head / tail repr: fp32 load, bf16 store to LDS (coalesced 16B/lane)
        float4 hr = *(const float4*)(node_repr + (size_t)hidx * 256 + c4);
        float4 tr = *(const float4*)(node_repr + (size_t)tidx * 256 + c4);
        ushort4 hb; hb.x = f2b(hr.x); hb.y = f2b(hr.y); hb.z = f2b(hr.z); hb.w = f2b(hr.w);
        ushort4 tb; tb.x = f2b(tr.x); tb.y = f2b(tr.y); tb.z = f2b(tr.z); tb.w = f2b(tr.w);
        *(ushort4*)(sX + (size_t)L * X_STRIDE + c4)       = hb;
        *(ushort4*)(sX + (size_t)L * X_STRIDE + 256 + c4) = tb;

        // masked mean over intersection set (fp32 accumulate)
        float a0 = 0.f, a1 = 0.f, a2 = 0.f, a3 = 0.f;
        int cnt = 0;
        const int* icp = inter + (size_t)g * 32;
        #pragma unroll 8
        for (int s = 0; s < 32; ++s) {
            const int ic = icp[s];
            if (ic != -1) {                       // sign(ic+1)==0 only when ic==-1
                const float sg = (ic >= 0) ? 1.f : -1.f;
                const int  idx = (ic >= 0) ? ic : -ic;
                float4 v = *(const float4*)(node_repr + (size_t)idx * 256 + c4);
                a0 += sg * v.x; a1 += sg * v.y;
                a2 += sg * v.z; a3 += sg * v.w;
                ++cnt;
            }
        }
        const float inv = 1.0f / (float)(cnt > 0 ? cnt : 1);
        ushort4 mv;
        mv.x = f2b(a0 * inv); mv.y = f2b(a1 * inv);
        mv.z = f2b(a2 * inv); mv.w = f2b(a3 * inv);
        *(ushort4*)(sX + (size_t)L * X_STRIDE + 544 + c4) = mv;

        if (lane < 32) {
            const float hf = node_feat[(size_t)hidx * 32 + lane];
            const float tf = node_feat[(size_t)tidx * 32 + lane];
            const float rv = rel_emb[(size_t)ridx * 32 + lane];
            sX[(size_t)L * X_STRIDE + 800 + lane] = f2b(hf);
            sX[(size_t)L * X_STRIDE + 832 + lane] = f2b(tf);
            sX[(size_t)L * X_STRIDE + 512 + lane] = f2b(rv);
            out_hf[(size_t)g * 32 + lane] = hf;   // exact fp32 copy
            out_tf[(size_t)g * 32 + lane] = tf;   // exact fp32 copy
        }
        sX[(size_t)L * X_STRIDE + 864 + lane] = f2b(dist_emb[(size_t)didx * 64 + lane]);
    }
    __syncthreads();

    // ---------- Phase 2: MFMA GEMM  X[32x928] @ W[928x128] ----------
    // wave w: m rows m0L..m0L+15 (m0L=(w&1)*16), n cols n0..n0+63 (n0=(w>>1)*64)
    const int col16 = lane & 15;
    const int quad  = lane >> 4;
    const int m0L   = (w & 1) * 16;
    const int n0    = (w >> 1) * 64;

    f32x4 accv[4] = {{0.f,0.f,0.f,0.f},{0.f,0.f,0.f,0.f},{0.f,0.f,0.f,0.f},{0.f,0.f,0.f,0.f}};

    const unsigned short* aP = sX + (size_t)(m0L + col16) * X_STRIDE + quad * 8;

    if (USE_WTC) {
        const unsigned short* bP0 = WTc + (size_t)(n0 +  0 + col16) * 928 + quad * 8;
        const unsigned short* bP1 = WTc + (size_t)(n0 + 16 + col16) * 928 + quad * 8;
        const unsigned short* bP2 = WTc + (size_t)(n0 + 32 + col16) * 928 + quad * 8;
        const unsigned short* bP3 = WTc + (size_t)(n0 + 48 + col16) * 928 + quad * 8;
        for (int ks = 0; ks < 29; ++ks) {
            const bf16x8 af = __builtin_bit_cast(bf16x8, *(const uint4*)(aP + ks * 32));
            bf16x8 b0 = __builtin_bit_cast(bf16x8, *(const uint4*)(bP0 + ks * 32));
            bf16x8 b1 = __builtin_bit_cast(bf16x8, *(const uint4*)(bP1 + ks * 32));
            bf16x8 b2 = __builtin_bit_cast(bf16x8, *(const uint4*)(bP2 + ks * 32));
            bf16x8 b3 = __builtin_bit_cast(bf16x8, *(const uint4*)(bP3 + ks * 32));
            accv[0] = __builtin_amdgcn_mfma_f32_16x16x32_bf16(af, b0, accv[0], 0, 0, 0);
            accv[1] = __builtin_amdgcn_mfma_f32_16x16x32_bf16(af, b1, accv[1], 0, 0, 0);
            accv[2] = __builtin_amdgcn_mfma_f32_16x16x32_bf16(af, b2, accv[2], 0, 0, 0);
            accv[3] = __builtin_amdgcn_mfma_f32_16x16x32_bf16(af, b3, accv[3], 0, 0, 0);
        }
    } else {
        for (int ks = 0; ks < 29; ++ks) {
            const int k0 = ks * 32 + quad * 8;
            const bf16x8 af = __builtin_bit_cast(bf16x8, *(const uint4*)(aP + ks * 32));
            bf16x8 b0 = gather_Bfrag(W1p, headWp, tailWp, n0 +  0 + col16, k0);
            bf16x8 b1 = gather_Bfrag(W1p, headWp, tailWp, n0 + 16 + col16, k0);
            bf16x8 b2 = gather_Bfrag(W1p, headWp, tailWp, n0 + 32 + col16, k0);
            bf16x8 b3 = gather_Bfrag(W1p, headWp, tailWp, n0 + 48 + col16, k0);
            accv[0] = __builtin_amdgcn_mfma_f32_16x16x32_bf16(af, b0, accv[0], 0, 0, 0);
            accv[1] = __builtin_amdgcn_mfma_f32_16x16x32_bf16(af, b1, accv[1], 0, 0, 0);
            accv[2] = __builtin_amdgcn_mfma_f32_16x16x32_bf16(af, b2, accv[2], 0, 0, 0);
            accv[3] = __builtin_amdgcn_mfma_f32_16x16x32_bf16(af, b3, accv[3], 0, 0, 0);
        }
    }

    // ---------- Epilogue (fp32 biases) ----------
    if (n0 == 0) {
        // h1 = relu(g_rep @ W1 + b1) -> LDS (bf16)
        #pragma unroll
        for (int t = 0; t < 4; ++t) {
            const int n = t * 16 + col16;
            const float bias = b1p[n];
            #pragma unroll
            for (int r = 0; r < 4; ++r) {
                float v = accv[t][r] + bias;
                v = v > 0.f ? v : 0.f;
                sH1[(size_t)(m0L + quad * 4 + r) * H1_STRIDE + n] = f2b(v);
            }
        }
    } else {
        // head_pred / tail_pred -> global fp32
        #pragma unroll
        for (int t = 0; t < 4; ++t) {
            const int nn = 64 + t * 16 + col16;
            const bool isH = nn < 96;
            const int c = isH ? (nn - 64) : (nn - 96);
            const float bias = isH ? head_bp[c] : tail_bp[c];
            float* dst = isH ? out_hp : out_tp;
            #pragma unroll
            for (int r = 0; r < 4; ++r) {
                const int m = g0 + m0L + quad * 4 + r;
                if (m < B) dst[(size_t)m * 32 + c] = accv[t][r] + bias;
            }
        }
    }
    __syncthreads();

    // ---------- Phase 3: h2 = relu(h1@W2+b2); out = h2@W3+b3 (fp32) ----------
    const int half = lane >> 5;      // 2 links per wave pass
    const int c    = lane & 31;
    const float w3v = W3p[c];
    const float b2v = b2p[c];
    const float b3v = b3p[0];
    for (int pass = 0; pass < 4; ++pass) {
        const int L = w * 8 + pass * 2 + half;
        float acc = 0.f;
        #pragma unroll 8
        for (int k = 0; k < 64; ++k)
            acc += b2f(sH1[(size_t)L * H1_STRIDE + k]) * W2p[(size_t)k * 32 + c];
        const float h2 = fmaxf(acc + b2v, 0.f);
        float p = h2 * w3v;
        p += __shfl_xor(p, 16);
        p += __shfl_xor(p, 8);
        p += __shfl_xor(p, 4);
        p += __shfl_xor(p, 2);
        p += __shfl_xor(p, 1);
        if (c == 0 && (g0 + L) < B) out0[g0 + L] = p + b3v;
    }
}

extern "C" void kernel_launch(void* const* d_in, const int* in_sizes, int n_in,
                              void* d_out, int out_size, void* d_ws, size_t ws_size,
                              hipStream_t stream) {
    const float* node_repr = (const float*)d_in[0];
    const float* node_feat = (const float*)d_in[1];
    const int* head_idx = (const int*)d_in[2];
    const int* rel_idx  = (const int*)d_in[3];
    const int* tail_idx = (const int*)d_in[4];
    const int* dist     = (const int*)d_in[5];
    const int* inter    = (const int*)d_in[6];
    const float* rel_emb  = (const float*)d_in[7];
    const float* dist_emb = (const float*)d_in[8];
    const float* head_W   = (const float*)d_in[9];
    const float* head_b   = (const float*)d_in[10];
    const float* tail_W   = (const float*)d_in[11];
    const float* tail_b   = (const float*)d_in[12];
    const float* W1       = (const float*)d_in[13];
    const float* b1       = (const float*)d_in[14];
    const float* W2       = (const float*)d_in[15];
    const float* b2       = (const float*)d_in[16];
    const float* W3       = (const float*)d_in[17];
    const float* b3       = (const float*)d_in[18];

    const int B = in_sizes[2];
    float* out = (float*)d_out;

    const int grid = (B + 31) / 32;
    const size_t lds = (size_t)32 * X_STRIDE * 2 + (size_t)32 * H1_STRIDE * 2;  // 64128 B

    if (ws_size >= (size_t)WTC_BYTES) {
        unsigned short* WTc = (unsigned short*)d_ws;   // 128*928 bf16 = 237568 B
        hipLaunchKernelGGL(prep_weights, dim3(128), dim3(256), 0, stream,
                           W1, head_W, tail_W, WTc);
        hipLaunchKernelGGL((fused_main<true>), dim3(grid), dim3(256), lds, stream,
                           node_repr, node_feat, head_idx, rel_idx, tail_idx, dist, inter,
                           rel_emb, dist_emb, b1, head_b, tail_b, W2, b2, W3, b3,
                           WTc, W1, head_W, tail_W, out, B);
    } else {
        hipLaunchKernelGGL((fused_main<false>), dim3(grid), dim3(256), lds, stream,
                           node_repr, node_feat, head_idx, rel_idx, tail_idx, dist, inter,
                           rel_emb, dist_emb, b1, head_b, tail_b, W2, b2, W3, b3,
                           (const unsigned short*)nullptr, W1, head_W, tail_W, out, B);
    }
}

// Round 4
// 260.967 us; speedup vs baseline: 1.3552x; 1.3552x over previous
//
#include <hip/hip_runtime.h>
#include <cstddef>
#include <cstdint>

typedef __bf16 bf16x8 __attribute__((ext_vector_type(8)));
typedef float  f32x4  __attribute__((ext_vector_type(4)));

#define NLINK 16       // links per block
#define X_STRIDE 936   // 928 cols + 8 pad (bf16) -> 468 dwords/row
#define H1_STRIDE 66
#define WTC_ELEMS (128 * 928)
#define WTC_BYTES (WTC_ELEMS * 2)

__device__ __forceinline__ float b2f(unsigned short u) {
    unsigned int x = (unsigned int)u << 16;
    return __builtin_bit_cast(float, x);
}
__device__ __forceinline__ unsigned short f2b(float f) {
    unsigned int u = __builtin_bit_cast(unsigned int, f);
    u += 0x7FFFu + ((u >> 16) & 1u);   // RNE
    return (unsigned short)(u >> 16);
}

// Build WTc[128][928] bf16 from fp32 weights (row-major, row = output col n, col = X col k).
//  n 0..63   : W1[k][n] for k<864, else 0
//  n 64..95  : head_W: X cols 544..799 -> rows 0..255, X cols 864..927 -> rows 256..319
//  n 96..127 : tail_W, same mapping
__global__ void prep_weights(const float* __restrict__ W1,
                             const float* __restrict__ headW,
                             const float* __restrict__ tailW,
                             unsigned short* __restrict__ WTc) {
    const int n = blockIdx.x;
    for (int k = threadIdx.x; k < 928; k += blockDim.x) {
        float v = 0.f;
        if (n < 64) {
            if (k < 864) v = W1[(size_t)k * 64 + n];
        } else {
            const int c = (n < 96) ? (n - 64) : (n - 96);
            const float* W = (n < 96) ? headW : tailW;
            if (k >= 544 && k < 800)      v = W[(size_t)(k - 544) * 32 + c];
            else if (k >= 864 && k < 928) v = W[(size_t)(256 + (k - 864)) * 32 + c];
        }
        WTc[(size_t)n * 928 + k] = f2b(v);
    }
}

// Fallback B-fragment gather straight from fp32 W1/headW/tailW natural layouts.
__device__ __forceinline__ bf16x8 gather_Bfrag(const float* __restrict__ W1,
                                               const float* __restrict__ hW,
                                               const float* __restrict__ tW,
                                               int n, int k0) {
    unsigned short r[8];
    if (n < 64) {
        #pragma unroll
        for (int j = 0; j < 8; ++j) {
            const int k = k0 + j;
            r[j] = (k < 864) ? f2b(W1[(size_t)k * 64 + n]) : (unsigned short)0;
        }
    } else {
        const float* W = (n < 96) ? hW : tW;
        const int c = (n < 96) ? (n - 64) : (n - 96);
        #pragma unroll
        for (int j = 0; j < 8; ++j) {
            const int k = k0 + j;
            float v = 0.f;
            if (k >= 544 && k < 800)      v = W[(size_t)(k - 544) * 32 + c];
            else if (k >= 864 && k < 928) v = W[(size_t)(256 + (k - 864)) * 32 + c];
            r[j] = f2b(v);
        }
    }
    unsigned short tmp[8];
    #pragma unroll
    for (int j = 0; j < 8; ++j) tmp[j] = r[j];
    return __builtin_bit_cast(bf16x8, *(const uint4*)tmp);
}

// X-row layout (bf16): [0,256) head_repr | [256,512) tail_repr | [512,544) rel_repr |
// [544,800) mid_repr | [800,832) head_feat | [832,864) tail_feat | [864,928) dist_repr
template <bool USE_WTC>
__global__ __launch_bounds__(256, 4) void fused_main(
    const float* __restrict__ node_repr,   // [N*256] fp32
    const float* __restrict__ node_feat,   // [N*32]  fp32
    const int* __restrict__ head_idx,
    const int* __restrict__ rel_idx,
    const int* __restrict__ tail_idx,
    const int* __restrict__ dist,
    const int* __restrict__ inter,         // [B*32]
    const float* __restrict__ rel_emb,     // [200*32]
    const float* __restrict__ dist_emb,    // [11*64]
    const float* __restrict__ b1p,         // [64]
    const float* __restrict__ head_bp,     // [32]
    const float* __restrict__ tail_bp,     // [32]
    const float* __restrict__ W2p,         // [64*32]
    const float* __restrict__ b2p,         // [32]
    const float* __restrict__ W3p,         // [32]
    const float* __restrict__ b3p,         // [1]
    const unsigned short* __restrict__ WTc,// [128*928] bf16 (only if USE_WTC)
    const float* __restrict__ W1p,         // natural fp32 layouts (fallback)
    const float* __restrict__ headWp,
    const float* __restrict__ tailWp,
    float* __restrict__ out,
    int B)
{
    extern __shared__ char smem[];
    unsigned short* sX  = (unsigned short*)smem;                          // NLINK*936 bf16 = 29952 B
    unsigned short* sH1 = (unsigned short*)(smem + NLINK * X_STRIDE * 2); // NLINK*66 bf16  =  2112 B

    const int tid  = threadIdx.x;
    const int w    = tid >> 6;
    const int lane = tid & 63;
    const int g0   = blockIdx.x * NLINK;

    float* out0   = out;
    float* out_hp = out + B;
    float* out_tp = out + B + (size_t)B * 32;
    float* out_hf = out + B + (size_t)B * 64;
    float* out_tf = out + B + (size_t)B * 96;

    // ---------- Phase 1: gather + build X tile (fp32 -> bf16), 4 links per wave ----------
    for (int li = 0; li < 4; ++li) {
        const int L = w * 4 + li;
        const int g = g0 + L;
        if (g >= B) continue;

        const int hidx = head_idx[g];
        const int tidx = tail_idx[g];
        const int ridx = rel_idx[g];
        const int didx = dist[g];
        const int c4 = lane * 4;

        // head / tail repr: fp32 load, bf16 store to LDS (coalesced 16B/lane)
        float4 hr = *(const float4*)(node_repr + (size_t)hidx * 256 + c4);
        float4 tr = *(const float4*)(node_repr + (size_t)tidx * 256 + c4);
        ushort4 hb; hb.x = f2b(hr.x); hb.y = f2b(hr.y); hb.z = f2b(hr.z); hb.w = f2b(hr.w);
        ushort4 tb; tb.x = f2b(tr.x); tb.y = f2b(tr.y); tb.z = f2b(tr.z); tb.w = f2b(tr.w);
        *(ushort4*)(sX + (size_t)L * X_STRIDE + c4)       = hb;
        *(ushort4*)(sX + (size_t)L * X_STRIDE + 256 + c4) = tb;

        // masked mean over intersection set — branchless, fully unrolled so the
        // compiler can keep many global_load_dwordx4 in flight per wave.
        float a0 = 0.f, a1 = 0.f, a2 = 0.f, a3 = 0.f;
        int cnt = 0;
        const int* icp = inter + (size_t)g * 32;
        #pragma unroll
        for (int s = 0; s < 32; ++s) {
            const int ic = icp[s];                 // wave-uniform -> s_load
            const int idx = (ic >= 0) ? ic : -ic;  // |ic|; ic==-1 -> row 1 (valid, masked)
            const float sg = (ic == -1) ? 0.f : ((ic >= 0) ? 1.f : -1.f);
            float4 v = *(const float4*)(node_repr + (size_t)idx * 256 + c4);
            a0 += sg * v.x; a1 += sg * v.y;
            a2 += sg * v.z; a3 += sg * v.w;
            cnt += (ic != -1) ? 1 : 0;
        }
        const float inv = 1.0f / (float)(cnt > 0 ? cnt : 1);
        ushort4 mv;
        mv.x = f2b(a0 * inv); mv.y = f2b(a1 * inv);
        mv.z = f2b(a2 * inv); mv.w = f2b(a3 * inv);
        *(ushort4*)(sX + (size_t)L * X_STRIDE + 544 + c4) = mv;

        if (lane < 32) {
            const float hf = node_feat[(size_t)hidx * 32 + lane];
            const float tf = node_feat[(size_t)tidx * 32 + lane];
            const float rv = rel_emb[(size_t)ridx * 32 + lane];
            sX[(size_t)L * X_STRIDE + 800 + lane] = f2b(hf);
            sX[(size_t)L * X_STRIDE + 832 + lane] = f2b(tf);
            sX[(size_t)L * X_STRIDE + 512 + lane] = f2b(rv);
            out_hf[(size_t)g * 32 + lane] = hf;   // exact fp32 copy
            out_tf[(size_t)g * 32 + lane] = tf;   // exact fp32 copy
        }
        sX[(size_t)L * X_STRIDE + 864 + lane] = f2b(dist_emb[(size_t)didx * 64 + lane]);
    }
    __syncthreads();

    // ---------- Phase 2: MFMA GEMM  X[16x928] @ W[928x128] ----------
    // wave w owns all 16 m-rows and n-cols [w*32, w*32+32): 2 acc tiles.
    const int col16 = lane & 15;
    const int quad  = lane >> 4;
    const int n0    = w * 32;

    f32x4 accv[2] = {{0.f,0.f,0.f,0.f},{0.f,0.f,0.f,0.f}};

    const unsigned short* aP = sX + (size_t)col16 * X_STRIDE + quad * 8;

    if (USE_WTC) {
        const unsigned short* bP0 = WTc + (size_t)(n0 +  0 + col16) * 928 + quad * 8;
        const unsigned short* bP1 = WTc + (size_t)(n0 + 16 + col16) * 928 + quad * 8;
        for (int ks = 0; ks < 29; ++ks) {
            const bf16x8 af = __builtin_bit_cast(bf16x8, *(const uint4*)(aP + ks * 32));
            bf16x8 b0 = __builtin_bit_cast(bf16x8, *(const uint4*)(bP0 + ks * 32));
            bf16x8 b1 = __builtin_bit_cast(bf16x8, *(const uint4*)(bP1 + ks * 32));
            accv[0] = __builtin_amdgcn_mfma_f32_16x16x32_bf16(af, b0, accv[0], 0, 0, 0);
            accv[1] = __builtin_amdgcn_mfma_f32_16x16x32_bf16(af, b1, accv[1], 0, 0, 0);
        }
    } else {
        for (int ks = 0; ks < 29; ++ks) {
            const int k0 = ks * 32 + quad * 8;
            const bf16x8 af = __builtin_bit_cast(bf16x8, *(const uint4*)(aP + ks * 32));
            bf16x8 b0 = gather_Bfrag(W1p, headWp, tailWp, n0 +  0 + col16, k0);
            bf16x8 b1 = gather_Bfrag(W1p, headWp, tailWp, n0 + 16 + col16, k0);
            accv[0] = __builtin_amdgcn_mfma_f32_16x16x32_bf16(af, b0, accv[0], 0, 0, 0);
            accv[1] = __builtin_amdgcn_mfma_f32_16x16x32_bf16(af, b1, accv[1], 0, 0, 0);
        }
    }

    // ---------- Epilogue (wave-uniform branches) ----------
    if (n0 < 64) {
        // waves 0,1: h1 = relu(. + b1) -> LDS bf16
        #pragma unroll
        for (int t = 0; t < 2; ++t) {
            const int n = n0 + t * 16 + col16;
            const float bias = b1p[n];
            #pragma unroll
            for (int r = 0; r < 4; ++r) {
                float v = accv[t][r] + bias;
                v = v > 0.f ? v : 0.f;
                sH1[(size_t)(quad * 4 + r) * H1_STRIDE + n] = f2b(v);
            }
        }
    } else {
        // wave 2: head_pred (cols 64..127 -> 0..31); wave 3: tail_pred
        const bool isH = (n0 < 96);
        const float* bp = isH ? head_bp : tail_bp;
        float* dst = isH ? out_hp : out_tp;
        #pragma unroll
        for (int t = 0; t < 2; ++t) {
            const int c = (n0 - (isH ? 64 : 96)) + t * 16 + col16;
            const float bias = bp[c];
            #pragma unroll
            for (int r = 0; r < 4; ++r) {
                const int m = g0 + quad * 4 + r;
                if (m < B) dst[(size_t)m * 32 + c] = accv[t][r] + bias;
            }
        }
    }
    __syncthreads();

    // ---------- Phase 3: h2 = relu(h1@W2+b2); out = h2@W3+b3 (fp32) ----------
    const int half = lane >> 5;      // 2 links per wave pass
    const int c    = lane & 31;
    const float w3v = W3p[c];
    const float b2v = b2p[c];
    const float b3v = b3p[0];
    #pragma unroll
    for (int pass = 0; pass < 2; ++pass) {
        const int L = w * 4 + pass * 2 + half;
        float acc = 0.f;
        #pragma unroll 8
        for (int k = 0; k < 64; ++k)
            acc += b2f(sH1[(size_t)L * H1_STRIDE + k]) * W2p[(size_t)k * 32 + c];
        const float h2 = fmaxf(acc + b2v, 0.f);
        float p = h2 * w3v;
        p += __shfl_xor(p, 16);
        p += __shfl_xor(p, 8);
        p += __shfl_xor(p, 4);
        p += __shfl_xor(p, 2);
        p += __shfl_xor(p, 1);
        if (c == 0 && (g0 + L) < B) out0[g0 + L] = p + b3v;
    }
}

extern "C" void kernel_launch(void* const* d_in, const int* in_sizes, int n_in,
                              void* d_out, int out_size, void* d_ws, size_t ws_size,
                              hipStream_t stream) {
    const float* node_repr = (const float*)d_in[0];
    const float* node_feat = (const float*)d_in[1];
    const int* head_idx = (const int*)d_in[2];
    const int* rel_idx  = (const int*)d_in[3];
    const int* tail_idx = (const int*)d_in[4];
    const int* dist     = (const int*)d_in[5];
    const int* inter    = (const int*)d_in[6];
    const float* rel_emb  = (const float*)d_in[7];
    const float* dist_emb = (const float*)d_in[8];
    const float* head_W   = (const float*)d_in[9];
    const float* head_b   = (const float*)d_in[10];
    const float* tail_W   = (const float*)d_in[11];
    const float* tail_b   = (const float*)d_in[12];
    const float* W1       = (const float*)d_in[13];
    const float* b1       = (const float*)d_in[14];
    const float* W2       = (const float*)d_in[15];
    const float* b2       = (const float*)d_in[16];
    const float* W3       = (const float*)d_in[17];
    const float* b3       = (const float*)d_in[18];

    const int B = in_sizes[2];
    float* out = (float*)d_out;

    const int grid = (B + NLINK - 1) / NLINK;
    const size_t lds = (size_t)NLINK * X_STRIDE * 2 + (size_t)NLINK * H1_STRIDE * 2;  // 32064 B

    if (ws_size >= (size_t)WTC_BYTES) {
        unsigned short* WTc = (unsigned short*)d_ws;   // 128*928 bf16 = 237568 B
        hipLaunchKernelGGL(prep_weights, dim3(128), dim3(256), 0, stream,
                           W1, head_W, tail_W, WTc);
        hipLaunchKernelGGL((fused_main<true>), dim3(grid), dim3(256), lds, stream,
                           node_repr, node_feat, head_idx, rel_idx, tail_idx, dist, inter,
                           rel_emb, dist_emb, b1, head_b, tail_b, W2, b2, W3, b3,
                           WTc, W1, head_W, tail_W, out, B);
    } else {
        hipLaunchKernelGGL((fused_main<false>), dim3(grid), dim3(256), lds, stream,
                           node_repr, node_feat, head_idx, rel_idx, tail_idx, dist, inter,
                           rel_emb, dist_emb, b1, head_b, tail_b, W2, b2, W3, b3,
                           (const unsigned short*)nullptr, W1, head_W, tail_W, out, B);
    }
}